// Round 4
// baseline (118.390 us; speedup 1.0000x reference)
//
#include <hip/hip_runtime.h>
#include <hip/hip_bf16.h>
#include <math.h>

#define L_IN   1048576
#define NBATCH 16
#define T_FR   2049                 // frames per batch
#define NFR    (NBATCH*T_FR)        // 32784 total frames
#define NBINS  513
#define KLEN   1024
#define HOP    512
#define PADL   512

#define XWORDS 1049600              // padded samples per batch (L_IN + 1024)
#define BROWS  1152                 // interleaved basis rows, padded (576 pairs)

#define BM 128
#define BN 256
#define BK 64
#define NKT (KLEN/BK)               // 16 K-tiles

#define NTX 129                     // frame tiles (256 each) -> 33024
#define NTY 9                       // basis-row tiles (128 each)
#define NWG (NTX*NTY)               // 1161

typedef __attribute__((ext_vector_type(8))) short short8;
typedef __attribute__((ext_vector_type(4))) float f32x4;

static __device__ __forceinline__ unsigned short f2bf(float f) {
  unsigned int u = __builtin_bit_cast(unsigned int, f);
  u += 0x7FFFu + ((u >> 16) & 1u);   // RNE
  return (unsigned short)(u >> 16);
}

static __device__ __forceinline__ unsigned long long pack4(float4 v) {
  return (unsigned long long)f2bf(v.x)
       | ((unsigned long long)f2bf(v.y) << 16)
       | ((unsigned long long)f2bf(v.z) << 32)
       | ((unsigned long long)f2bf(v.w) << 48);
}

#define GLOAD_LDS16(gsrc, ldst) \
  __builtin_amdgcn_global_load_lds((const __attribute__((address_space(1))) void*)(gsrc), \
                                   (__attribute__((address_space(3))) void*)(ldst), 16, 0, 0)

// ---------------- prep: basis fp32 -> bf16, interleaved [pair][{R,I}][1024] ----------------
__global__ void prep_basis(const float* __restrict__ basis, unsigned short* __restrict__ Bb) {
  const int row = blockIdx.x;          // 0..1151
  const int p = row >> 1, s = row & 1;
  unsigned long long v = 0ull;
  if (p < NBINS) {
    const int srcRow = s ? (p + NBINS) : p;   // imag rows live at 513..1025
    float4 x = *(const float4*)&basis[(long)srcRow * KLEN + threadIdx.x * 4];
    v = pack4(x);
  }
  *(unsigned long long*)(Bb + (long)row * KLEN + threadIdx.x * 4) = v;
}

// ---------------- prep: reflect-padded input fp32 -> bf16, X[16][1049600] ----------------
__global__ void prep_x(const float* __restrict__ input, unsigned short* __restrict__ Xb) {
  const int b  = blockIdx.y;
  const int j0 = blockIdx.x * 1024 + threadIdx.x * 4;   // 1025*1024 == 1049600 exactly
  const int s0 = j0 - PADL;
  float4 x;
  if (s0 >= 0 && s0 + 3 < L_IN) {
    x = *(const float4*)&input[(long)b * L_IN + s0];
  } else {
    float e[4];
    #pragma unroll
    for (int q = 0; q < 4; ++q) {
      int s = s0 + q;
      s = s < 0 ? -s : s;
      s = s >= L_IN ? (2 * L_IN - 2 - s) : s;
      e[q] = input[(long)b * L_IN + s];
    }
    x.x = e[0]; x.y = e[1]; x.z = e[2]; x.w = e[3];
  }
  *(unsigned long long*)(Xb + (long)b * XWORDS + j0) = pack4(x);
}

// ---------------- main: 128x256 tile, 8 waves, triple-buffer, counted-vmcnt phase schedule ----
// LDS chunk swizzle: physical 16B-chunk = logical chunk ^ (row & 7); gload_lds dest LINEAR,
// global SOURCE inverse-swizzled per lane (rule 21); ds_reads apply the same XOR.
__global__ __launch_bounds__(512, 2)
void stft_main(const unsigned short* __restrict__ Xb,
               const unsigned short* __restrict__ Bb,
               float* __restrict__ out)
{
  __shared__ unsigned short sA[3][BM][BK];   // 3 x 16 KB
  __shared__ unsigned short sB[3][BN][BK];   // 3 x 32 KB   (total 144 KB)

  const int tid  = threadIdx.x;
  const int lane = tid & 63;
  const int w    = tid >> 6;               // wave 0..7

  // ---- bijective XCD swizzle (m204), y-fast: 9 consecutive wg share one frame slab ----
  const int bid = blockIdx.x;
  const int qq = NWG >> 3, rr = NWG & 7;   // 145, 1
  const int xcd = bid & 7, idx = bid >> 3;
  const int wg = (xcd < rr) ? (xcd * (qq + 1) + idx) : (rr * (qq + 1) + (xcd - rr) * qq + idx);
  const int frameBase = (wg / NTY) * BN;
  const int rowBase   = (wg % NTY) * BM;

  // ---- staging source pointers: instr i covers rows i*64 + w*8 + (lane>>3), chunk lane&7 ----
  const int lr8 = lane >> 3;               // row within 8-row group (== row & 7)
  const int lc8 = lane & 7;                // physical 16B chunk
  const int cs  = (lc8 ^ lr8) * 8;         // inverse-swizzled source offset (shorts)

  const unsigned short* aP0 = Bb + (long)(rowBase +       w * 8 + lr8) * KLEN + cs;
  const unsigned short* aP1 = Bb + (long)(rowBase + 64  + w * 8 + lr8) * KLEN + cs;
  const unsigned short* bP[4];
  #pragma unroll
  for (int i = 0; i < 4; ++i) {
    int frame = frameBase + i * 64 + w * 8 + lr8;
    if (frame > NFR - 1) frame = NFR - 1;
    const int bb = frame / T_FR;
    const int t  = frame - bb * T_FR;
    bP[i] = Xb + (long)bb * XWORDS + t * HOP + cs;
  }

  const int lr = lane & 15;
  const int ql = lane >> 4;                // quarter-wave -> base chunk
  const int e8 = lane & 7;                 // row&7 for fragment rows
  const int wr = (w >> 2) * 64;            // wave's basis-row offset in tile
  const int wc = (w & 3) * 64;             // wave's frame offset in tile

  f32x4 acc[4][4];
  #pragma unroll
  for (int m = 0; m < 4; ++m)
    #pragma unroll
    for (int n = 0; n < 4; ++n) acc[m][n] = (f32x4){0.f, 0.f, 0.f, 0.f};

  #define STAGE_P0(kt) do { const int cb_ = (kt) % 3;                        \
    GLOAD_LDS16(aP0  + (kt) * 64, &sA[cb_][      w * 8][0]);                 \
    GLOAD_LDS16(aP1  + (kt) * 64, &sA[cb_][ 64 + w * 8][0]);                 \
    GLOAD_LDS16(bP[0]+ (kt) * 64, &sB[cb_][      w * 8][0]);                 \
  } while (0)
  #define STAGE_P1(kt) do { const int cb_ = (kt) % 3;                        \
    GLOAD_LDS16(bP[1]+ (kt) * 64, &sB[cb_][ 64 + w * 8][0]);                 \
    GLOAD_LDS16(bP[2]+ (kt) * 64, &sB[cb_][128 + w * 8][0]);                 \
    GLOAD_LDS16(bP[3]+ (kt) * 64, &sB[cb_][192 + w * 8][0]);                 \
  } while (0)

  // one phase: 8 ds_read_b128 + 3 gload_lds prefetch + barrier + 16 MFMA (setprio-wrapped)
  #define PHASE(cb, kk, DO_STAGE) do {                                       \
    const int c_ = (((kk) * 4 + ql) ^ e8) * 8;                               \
    short8 a_[4], b_[4];                                                     \
    _Pragma("unroll")                                                        \
    for (int m = 0; m < 4; ++m) a_[m] = *(const short8*)&sA[cb][wr + m * 16 + lr][c_]; \
    _Pragma("unroll")                                                        \
    for (int n = 0; n < 4; ++n) b_[n] = *(const short8*)&sB[cb][wc + n * 16 + lr][c_]; \
    DO_STAGE;                                                                \
    __builtin_amdgcn_s_barrier();                                            \
    asm volatile("s_waitcnt lgkmcnt(0)" ::: "memory");                       \
    __builtin_amdgcn_sched_barrier(0);                                       \
    __builtin_amdgcn_s_setprio(1);                                           \
    _Pragma("unroll")                                                        \
    for (int m = 0; m < 4; ++m)                                              \
      _Pragma("unroll")                                                      \
      for (int n = 0; n < 4; ++n)                                            \
        acc[m][n] = __builtin_amdgcn_mfma_f32_16x16x32_bf16(a_[m], b_[n], acc[m][n], 0, 0, 0); \
    __builtin_amdgcn_s_setprio(0);                                           \
    __builtin_amdgcn_sched_barrier(0);                                       \
    __builtin_amdgcn_s_barrier();                                            \
  } while (0)

  // ---- prologue: 2 K-tiles in flight (12 loads/thread) ----
  STAGE_P0(0); STAGE_P1(0);
  STAGE_P0(1); STAGE_P1(1);

  // ---- main loop: counted vmcnt(6) retires exactly tile kt; kt+1 (and kt+2) stay in flight ----
  for (int kt = 0; kt < NKT - 1; ++kt) {
    const int cb = kt % 3;
    asm volatile("s_waitcnt vmcnt(6)" ::: "memory");
    __builtin_amdgcn_s_barrier();
    if (kt < NKT - 2) { PHASE(cb, 0, STAGE_P0(kt + 2)); }
    else              { PHASE(cb, 0, ((void)0));        }
    if (kt < NKT - 2) { PHASE(cb, 1, STAGE_P1(kt + 2)); }
    else              { PHASE(cb, 1, ((void)0));        }
  }
  // ---- peeled last K-tile (15 % 3 == 0) ----
  asm volatile("s_waitcnt vmcnt(0)" ::: "memory");
  __builtin_amdgcn_s_barrier();
  PHASE(0, 0, ((void)0));
  PHASE(0, 1, ((void)0));

  #undef STAGE_P0
  #undef STAGE_P1
  #undef PHASE

  // ---- epilogue: magnitude; regs j = {R(p), I(p), R(p+1), I(p+1)} ----
  #pragma unroll
  for (int n = 0; n < 4; ++n) {
    const int frame = frameBase + wc + n * 16 + lr;
    if (frame >= NFR) continue;
    const int bb = frame / T_FR;
    const int t  = frame - bb * T_FR;
    const long ob = (long)bb * NBINS * T_FR + t;
    #pragma unroll
    for (int m = 0; m < 4; ++m) {
      const int grow = rowBase + wr + m * 16 + ql * 4;  // even
      const int p = grow >> 1;
      if (p < NBINS) {
        float re = acc[m][n][0], im = acc[m][n][1];
        out[ob + (long)p * T_FR] = sqrtf(re * re + im * im);
      }
      if (p + 1 < NBINS) {
        float re = acc[m][n][2], im = acc[m][n][3];
        out[ob + (long)(p + 1) * T_FR] = sqrtf(re * re + im * im);
      }
    }
  }
}

// ---------------- fallback (round-1 kernel) if ws is too small ----------------
#define FBM 64
#define FBN 64
#define FPITCH 72
__global__ __launch_bounds__(256, 2)
void stft_fallback(const float* __restrict__ input,
                   const float* __restrict__ basis,
                   float* __restrict__ out)
{
  __shared__ unsigned short sX[FBN][FPITCH];
  __shared__ unsigned short sR[FBM][FPITCH];
  __shared__ unsigned short sI[FBM][FPITCH];
  const int tid = threadIdx.x;
  const int frameBase = blockIdx.x * FBN;
  const int binBase   = blockIdx.y * FBM;
  const int r0 = tid >> 4;
  const int kg = tid & 15;
  long xbase[4]; int xs0[4];
  const float* bR[4]; const float* bI[4];
  #pragma unroll
  for (int i = 0; i < 4; ++i) {
    int r = r0 + i * 16;
    int frame = frameBase + r;
    int fcl = frame < NFR ? frame : (NFR - 1);
    unsigned int bb = (unsigned int)fcl / 2049u;
    int t = fcl - (int)(bb * 2049u);
    xbase[i] = (long)bb * L_IN;
    xs0[i]   = t * HOP - PADL + kg * 4;
    int bin = binBase + r;
    int rr = bin < 512 ? bin : 512;
    int ri = bin + 513; ri = ri < 1025 ? ri : 1025;
    bR[i] = basis + (long)rr * KLEN + kg * 4;
    bI[i] = basis + (long)ri * KLEN + kg * 4;
  }
  const int lane = tid & 63;
  const int wid  = tid >> 6;
  const int wrow = (wid >> 1) * 32;
  const int wcol = (wid & 1) * 32;
  const int lr   = lane & 15;
  const int koff = (lane >> 4) * 8;
  f32x4 zero = {0.f, 0.f, 0.f, 0.f};
  f32x4 accR[2][2], accI[2][2];
  #pragma unroll
  for (int m = 0; m < 2; ++m)
    #pragma unroll
    for (int n = 0; n < 2; ++n) { accR[m][n] = zero; accI[m][n] = zero; }
  for (int ks = 0; ks < KLEN / 64; ++ks) {
    const int k0 = ks * 64;
    #pragma unroll
    for (int i = 0; i < 4; ++i) {
      const int r = r0 + i * 16;
      int s0 = xs0[i] + k0;
      float4 xv;
      if (s0 >= 0 && s0 + 3 < L_IN) {
        xv = *(const float4*)&input[xbase[i] + s0];
      } else {
        float ee[4];
        #pragma unroll
        for (int q = 0; q < 4; ++q) {
          int s = s0 + q;
          s = s < 0 ? -s : s;
          s = s >= L_IN ? (2 * L_IN - 2 - s) : s;
          ee[q] = input[xbase[i] + s];
        }
        xv.x = ee[0]; xv.y = ee[1]; xv.z = ee[2]; xv.w = ee[3];
      }
      *(unsigned long long*)&sX[r][kg * 4] = pack4(xv);
      float4 rv = *(const float4*)(bR[i] + k0);
      *(unsigned long long*)&sR[r][kg * 4] = pack4(rv);
      float4 iv = *(const float4*)(bI[i] + k0);
      *(unsigned long long*)&sI[r][kg * 4] = pack4(iv);
    }
    __syncthreads();
    #pragma unroll
    for (int kk = 0; kk < 2; ++kk) {
      const int k = kk * 32 + koff;
      short8 a0 = *(const short8*)&sR[wrow + lr][k];
      short8 a1 = *(const short8*)&sR[wrow + 16 + lr][k];
      short8 c0 = *(const short8*)&sI[wrow + lr][k];
      short8 c1 = *(const short8*)&sI[wrow + 16 + lr][k];
      short8 b0 = *(const short8*)&sX[wcol + lr][k];
      short8 b1 = *(const short8*)&sX[wcol + 16 + lr][k];
      accR[0][0] = __builtin_amdgcn_mfma_f32_16x16x32_bf16(a0, b0, accR[0][0], 0, 0, 0);
      accR[0][1] = __builtin_amdgcn_mfma_f32_16x16x32_bf16(a0, b1, accR[0][1], 0, 0, 0);
      accR[1][0] = __builtin_amdgcn_mfma_f32_16x16x32_bf16(a1, b0, accR[1][0], 0, 0, 0);
      accR[1][1] = __builtin_amdgcn_mfma_f32_16x16x32_bf16(a1, b1, accR[1][1], 0, 0, 0);
      accI[0][0] = __builtin_amdgcn_mfma_f32_16x16x32_bf16(c0, b0, accI[0][0], 0, 0, 0);
      accI[0][1] = __builtin_amdgcn_mfma_f32_16x16x32_bf16(c0, b1, accI[0][1], 0, 0, 0);
      accI[1][0] = __builtin_amdgcn_mfma_f32_16x16x32_bf16(c1, b0, accI[1][0], 0, 0, 0);
      accI[1][1] = __builtin_amdgcn_mfma_f32_16x16x32_bf16(c1, b1, accI[1][1], 0, 0, 0);
    }
    __syncthreads();
  }
  #pragma unroll
  for (int n = 0; n < 2; ++n) {
    int frame = frameBase + wcol + n * 16 + lr;
    if (frame >= NFR) continue;
    unsigned int bb = (unsigned int)frame / 2049u;
    int t = frame - (int)(bb * 2049u);
    long obase = (long)bb * NBINS * T_FR + t;
    #pragma unroll
    for (int m = 0; m < 2; ++m) {
      int binB = binBase + wrow + m * 16 + (lane >> 4) * 4;
      #pragma unroll
      for (int j = 0; j < 4; ++j) {
        int bin = binB + j;
        if (bin < NBINS) {
          float re = accR[m][n][j];
          float im = accI[m][n][j];
          out[obase + (long)bin * T_FR] = sqrtf(re * re + im * im);
        }
      }
    }
  }
}

extern "C" void kernel_launch(void* const* d_in, const int* in_sizes, int n_in,
                              void* d_out, int out_size, void* d_ws, size_t ws_size,
                              hipStream_t stream) {
  const float* input = (const float*)d_in[0];
  const float* basis = (const float*)d_in[1];
  float* out = (float*)d_out;

  const size_t xBytes = (size_t)NBATCH * XWORDS * 2;
  const size_t bBytes = (size_t)BROWS * KLEN * 2;
  if (ws_size >= xBytes + bBytes) {
    unsigned short* Xb = (unsigned short*)d_ws;
    unsigned short* Bb = Xb + (size_t)NBATCH * XWORDS;
    prep_x<<<dim3(1025, 16), 256, 0, stream>>>(input, Xb);
    prep_basis<<<dim3(BROWS), 256, 0, stream>>>(basis, Bb);
    stft_main<<<dim3(NWG), 512, 0, stream>>>(Xb, Bb, out);
  } else {
    dim3 grid((NFR + FBN - 1) / FBN, (NBINS + FBM - 1) / FBM);
    stft_fallback<<<grid, dim3(256), 0, stream>>>(input, basis, out);
  }
}

// Round 5
// 114.730 us; speedup vs baseline: 1.0319x; 1.0319x over previous
//
#include <hip/hip_runtime.h>
#include <hip/hip_bf16.h>
#include <math.h>

#define L_IN   1048576
#define NBATCH 16
#define T_FR   2049                 // frames per batch
#define NFR    (NBATCH*T_FR)        // 32784 total frames
#define NBINS  513
#define KLEN   1024
#define HOP    512
#define PADL   512

#define XWORDS 1049600              // padded samples per batch (L_IN + 1024)
#define BROWS2 1024                 // packed basis rows (512 pairs, pair0 = {bin0R, bin512R})

#define BM 256
#define BN 256
#define BK 64
#define NKT (KLEN/BK)               // 16 K-tiles -> 8 double-iters

#define NTX 128                     // frame tiles (256 each) -> frames 0..32767
#define NTY 4                       // basis-row tiles (256 each)
#define NWG (NTX*NTY)               // 512 == 2 x 256 CUs exactly

typedef __attribute__((ext_vector_type(8))) short short8;
typedef __attribute__((ext_vector_type(4))) float f32x4;

static __device__ __forceinline__ unsigned short f2bf(float f) {
  unsigned int u = __builtin_bit_cast(unsigned int, f);
  u += 0x7FFFu + ((u >> 16) & 1u);   // RNE
  return (unsigned short)(u >> 16);
}

static __device__ __forceinline__ unsigned long long pack4(float4 v) {
  return (unsigned long long)f2bf(v.x)
       | ((unsigned long long)f2bf(v.y) << 16)
       | ((unsigned long long)f2bf(v.z) << 32)
       | ((unsigned long long)f2bf(v.w) << 48);
}

#define GLOAD_LDS16(gsrc, ldst) \
  __builtin_amdgcn_global_load_lds((const __attribute__((address_space(1))) void*)(gsrc), \
                                   (__attribute__((address_space(3))) void*)(ldst), 16, 0, 0)

// ---------------- prep: basis fp32 -> bf16, packed 1024 rows ----------------
// row r: p=r>>1, s=r&1.  p==0: {real bin0, real bin512}; p>=1: {real p, imag p}.
__global__ void prep_basis2(const float* __restrict__ basis, unsigned short* __restrict__ Bb) {
  const int row = blockIdx.x;          // 0..1023
  const int p = row >> 1, s = row & 1;
  const int src = (p == 0) ? (s ? 512 : 0) : (s ? (513 + p) : p);
  float4 x = *(const float4*)&basis[(long)src * KLEN + threadIdx.x * 4];
  *(unsigned long long*)(Bb + (long)row * KLEN + threadIdx.x * 4) = pack4(x);
}

// ---------------- prep: reflect-padded input fp32 -> bf16, X[16][1049600] ----------------
__global__ void prep_x(const float* __restrict__ input, unsigned short* __restrict__ Xb) {
  const int b  = blockIdx.y;
  const int j0 = blockIdx.x * 1024 + threadIdx.x * 4;   // 1025*1024 == 1049600 exactly
  const int s0 = j0 - PADL;
  float4 x;
  if (s0 >= 0 && s0 + 3 < L_IN) {
    x = *(const float4*)&input[(long)b * L_IN + s0];
  } else {
    float e[4];
    #pragma unroll
    for (int q = 0; q < 4; ++q) {
      int s = s0 + q;
      s = s < 0 ? -s : s;
      s = s >= L_IN ? (2 * L_IN - 2 - s) : s;
      e[q] = input[(long)b * L_IN + s];
    }
    x.x = e[0]; x.y = e[1]; x.z = e[2]; x.w = e[3];
  }
  *(unsigned long long*)(Xb + (long)b * XWORDS + j0) = pack4(x);
}

// ---------------- tail: last 16 frames (batch 15, t=2033..2048), fp32 direct ----------------
__global__ void stft_tail(const unsigned short* __restrict__ Xb,
                          const float* __restrict__ basis,
                          float* __restrict__ out) {
  __shared__ float xs[KLEN];
  __shared__ float sred[57][4];
  const int fi = blockIdx.y;          // 0..15
  const int t  = 2033 + fi;
  const int bt = blockIdx.x;          // 0..8
  const int tid = threadIdx.x;
  const unsigned short* xw = Xb + (long)15 * XWORDS + t * HOP;
  for (int i = tid; i < KLEN; i += 256) {
    unsigned int u = (unsigned int)xw[i] << 16;
    xs[i] = __builtin_bit_cast(float, u);
  }
  __syncthreads();
  const int bi = tid >> 2;            // 0..63
  const int q  = tid & 3;             // bit0 = k-half, bit1 = re/im
  const int bin = bt * 57 + bi;
  if (bi < 57 && bin < NBINS) {
    const int row = (q >> 1) ? (513 + bin) : bin;
    const int k0 = (q & 1) * 512;
    const float* br = basis + (long)row * KLEN + k0;
    float s = 0.f;
    for (int i = 0; i < 512; i += 4) {
      float4 v = *(const float4*)&br[i];
      s += v.x * xs[k0 + i] + v.y * xs[k0 + i + 1] + v.z * xs[k0 + i + 2] + v.w * xs[k0 + i + 3];
    }
    sred[bi][q] = s;
  }
  __syncthreads();
  if (bi < 57 && bin < NBINS && q == 0) {
    float re = sred[bi][0] + sred[bi][1];
    float im = sred[bi][2] + sred[bi][3];
    out[(long)15 * NBINS * T_FR + (long)bin * T_FR + t] = sqrtf(re * re + im * im);
  }
}

// ---------------- main: 256x256x64, 8 waves (2Mx4N, 128x64 each), m201 8-phase schedule ----
__global__ __launch_bounds__(512, 2)
void stft_main(const unsigned short* __restrict__ Xb,
               const unsigned short* __restrict__ Bb,
               float* __restrict__ out)
{
  __shared__ unsigned short sA[2][256][64];   // [tile-parity][row][k]  64 KB
  __shared__ unsigned short sB[2][256][64];   // [tile-parity][frame][k] 64 KB

  const int tid  = threadIdx.x;
  const int lane = tid & 63;
  const int w    = tid >> 6;               // wave 0..7

  // ---- XCD swizzle: NWG=512 -> wg = xcd*64 + idx (bijective); y-fast for Xb slab reuse ----
  const int bid = blockIdx.x;
  const int wg  = (bid & 7) * 64 + (bid >> 3);
  const int frameBase = (wg >> 2) * BN;    // tileX = wg/4
  const int rowBase   = (wg & 3) * BM;     // tileY = wg%4

  // ---- staging pointers: half h, instr i covers rows h*128 + i*64 + w*8 + (lane>>3) ----
  const int lr8 = lane >> 3;               // row within 8-row group (== row&7)
  const int lc8 = lane & 7;                // physical 16B chunk
  const int cs  = (lc8 ^ lr8) * 8;         // inverse-swizzled source offset (shorts)

  const unsigned short* aPtr[4];
  const unsigned short* bPtr[4];
  #pragma unroll
  for (int hi = 0; hi < 4; ++hi) {
    const int h = hi >> 1, i = hi & 1;
    const int r = h * 128 + i * 64 + w * 8 + lr8;
    aPtr[hi] = Bb + (long)(rowBase + r) * KLEN + cs;
    const int frame = frameBase + r;       // <= 32767, always valid
    const int bb = frame / T_FR;
    const int t  = frame - bb * T_FR;
    bPtr[hi] = Xb + (long)bb * XWORDS + t * HOP + cs;
  }

  const int lr = lane & 15;
  const int ql = lane >> 4;                // 0..3
  const int e8 = lr & 7;                   // == fragment row & 7
  const int wr = (w >> 2) * 128;           // wave's basis-row offset (2 M-halves)
  const int wc = (w & 3) * 64;             // wave's frame offset (4 N-quarters)
  const int c0 = ((ql)     ^ e8) * 8;      // swizzled chunk offset, k-slot 0
  const int c1 = ((4 + ql) ^ e8) * 8;      // k-slot 1

  f32x4 acc[8][4];
  #pragma unroll
  for (int m = 0; m < 8; ++m)
    #pragma unroll
    for (int n = 0; n < 4; ++n) acc[m][n] = (f32x4){0.f, 0.f, 0.f, 0.f};

  short8 bf[4][2];                          // B-frags, held across the 4 quad-phases of a tile

  #define SA(par, h, koff) do {                                              \
    GLOAD_LDS16(aPtr[(h)*2]     + (koff), &sA[par][(h)*128      + w*8][0]);  \
    GLOAD_LDS16(aPtr[(h)*2 + 1] + (koff), &sA[par][(h)*128 + 64 + w*8][0]);  \
  } while (0)
  #define SB(par, h, koff) do {                                              \
    GLOAD_LDS16(bPtr[(h)*2]     + (koff), &sB[par][(h)*128      + w*8][0]);  \
    GLOAD_LDS16(bPtr[(h)*2 + 1] + (koff), &sB[par][(h)*128 + 64 + w*8][0]);  \
  } while (0)

  #define VM4  asm volatile("s_waitcnt vmcnt(4)" ::: "memory")
  #define NOPS ((void)0)

  // one phase: [B-reads if q0] + A-quad reads + 1 half-tile stage + barrier + 16 MFMA + barrier
  #define PHASE(par, q, READB, STAGE_STMT, VM_STMT) do {                     \
    if (READB) {                                                             \
      _Pragma("unroll")                                                      \
      for (int n = 0; n < 4; ++n) {                                          \
        bf[n][0] = *(const short8*)&sB[par][wc + n * 16 + lr][c0];           \
        bf[n][1] = *(const short8*)&sB[par][wc + n * 16 + lr][c1];           \
      }                                                                      \
    }                                                                        \
    short8 aq[2][2];                                                         \
    aq[0][0] = *(const short8*)&sA[par][wr + (2*(q))     * 16 + lr][c0];     \
    aq[0][1] = *(const short8*)&sA[par][wr + (2*(q))     * 16 + lr][c1];     \
    aq[1][0] = *(const short8*)&sA[par][wr + (2*(q) + 1) * 16 + lr][c0];     \
    aq[1][1] = *(const short8*)&sA[par][wr + (2*(q) + 1) * 16 + lr][c1];     \
    STAGE_STMT;                                                              \
    __builtin_amdgcn_s_barrier();                                            \
    asm volatile("s_waitcnt lgkmcnt(0)" ::: "memory");                       \
    __builtin_amdgcn_sched_barrier(0);                                       \
    __builtin_amdgcn_s_setprio(1);                                           \
    _Pragma("unroll")                                                        \
    for (int mi = 0; mi < 2; ++mi)                                           \
      _Pragma("unroll")                                                      \
      for (int n = 0; n < 4; ++n)                                            \
        _Pragma("unroll")                                                    \
        for (int k = 0; k < 2; ++k)                                          \
          acc[2*(q) + mi][n] =                                               \
            __builtin_amdgcn_mfma_f32_16x16x32_bf16(aq[mi][k], bf[n][k],     \
                                                    acc[2*(q) + mi][n], 0, 0, 0); \
    __builtin_amdgcn_s_setprio(0);                                           \
    __builtin_amdgcn_sched_barrier(0);                                       \
    VM_STMT;                                                                 \
    __builtin_amdgcn_s_barrier();                                            \
    __builtin_amdgcn_sched_barrier(0);                                       \
  } while (0)

  // ---- prologue: B(0), A(0), B(1) staged (12 gloads); join so tile0 is readable ----
  SB(0, 0, 0);  SB(0, 1, 0);
  SA(0, 0, 0);  SA(0, 1, 0);
  SB(1, 0, 64); SB(1, 1, 64);
  asm volatile("s_waitcnt vmcnt(4)" ::: "memory");   // B(0)+A(0) landed; B(1) in flight
  __builtin_amdgcn_s_barrier();
  __builtin_amdgcn_sched_barrier(0);

  // ---- main loop: 8 iters x 2 K-tiles x 4 quad-phases; vmcnt(4) at phases 4 & 8 only ----
  for (int j = 0; j < 8; ++j) {
    const int o1 = (2*j + 1) * 64;   // A(t1)
    const int o2 = (2*j + 2) * 64;   // tile t0+2 (j==7: benign overread, ws guard)
    const int o3 = (2*j + 3) * 64;   // B(t1+2)
    PHASE(0, 0, 1, SA(1, 0, o1), NOPS);   // t0 reads; stage A-h0(t1)  [A-odd freed prev ph8]
    PHASE(0, 1, 0, SA(1, 1, o1), NOPS);   //            stage A-h1(t1)
    PHASE(0, 2, 0, SB(0, 0, o2), NOPS);   //            stage B-h0(t0+2) [B-even freed ph1]
    PHASE(0, 3, 0, SB(0, 1, o2), VM4);    //            stage B-h1(t0+2); join for t1
    PHASE(1, 0, 1, SA(0, 0, o2), NOPS);   // t1 reads; stage A-h0(t0+2) [A-even freed ph4]
    PHASE(1, 1, 0, SA(0, 1, o2), NOPS);   //            stage A-h1(t0+2)
    PHASE(1, 2, 0, SB(1, 0, o3), NOPS);   //            stage B-h0(t1+2) [B-odd freed ph5]
    PHASE(1, 3, 0, SB(1, 1, o3), VM4);    //            stage B-h1(t1+2); join for next t0
  }

  #undef PHASE
  #undef SA
  #undef SB
  #undef VM4
  #undef NOPS

  // ---- epilogue: pairs {R,I} lane-local; pair0 = {bin0, bin512} -> plain |.| ----
  #pragma unroll
  for (int n = 0; n < 4; ++n) {
    const int frame = frameBase + wc + n * 16 + lr;   // < 32768 always
    const int bb = frame / T_FR;
    const int t  = frame - bb * T_FR;
    const long ob = (long)bb * NBINS * T_FR + t;
    #pragma unroll
    for (int m = 0; m < 8; ++m) {
      const int grow = rowBase + wr + m * 16 + ql * 4;  // multiple of 4
      const int p0 = grow >> 1;                          // even pair index
      const float x0 = acc[m][n][0], x1 = acc[m][n][1];
      const float x2 = acc[m][n][2], x3 = acc[m][n][3];
      if (p0 == 0) {
        out[ob]                    = fabsf(x0);          // bin 0
        out[ob + (long)512 * T_FR] = fabsf(x1);          // bin 512
      } else {
        out[ob + (long)p0 * T_FR] = sqrtf(x0 * x0 + x1 * x1);
      }
      out[ob + (long)(p0 + 1) * T_FR] = sqrtf(x2 * x2 + x3 * x3);  // bins 1..511
    }
  }
}

// ---------------- fallback (round-1 kernel) if ws is too small ----------------
#define FBM 64
#define FBN 64
#define FPITCH 72
__global__ __launch_bounds__(256, 2)
void stft_fallback(const float* __restrict__ input,
                   const float* __restrict__ basis,
                   float* __restrict__ out)
{
  __shared__ unsigned short sX[FBN][FPITCH];
  __shared__ unsigned short sR[FBM][FPITCH];
  __shared__ unsigned short sI[FBM][FPITCH];
  const int tid = threadIdx.x;
  const int frameBase = blockIdx.x * FBN;
  const int binBase   = blockIdx.y * FBM;
  const int r0 = tid >> 4;
  const int kg = tid & 15;
  long xbase[4]; int xs0[4];
  const float* bR[4]; const float* bI[4];
  #pragma unroll
  for (int i = 0; i < 4; ++i) {
    int r = r0 + i * 16;
    int frame = frameBase + r;
    int fcl = frame < NFR ? frame : (NFR - 1);
    unsigned int bb = (unsigned int)fcl / 2049u;
    int t = fcl - (int)(bb * 2049u);
    xbase[i] = (long)bb * L_IN;
    xs0[i]   = t * HOP - PADL + kg * 4;
    int bin = binBase + r;
    int rr = bin < 512 ? bin : 512;
    int ri = bin + 513; ri = ri < 1025 ? ri : 1025;
    bR[i] = basis + (long)rr * KLEN + kg * 4;
    bI[i] = basis + (long)ri * KLEN + kg * 4;
  }
  const int lane = tid & 63;
  const int wid  = tid >> 6;
  const int wrow = (wid >> 1) * 32;
  const int wcol = (wid & 1) * 32;
  const int lr   = lane & 15;
  const int koff = (lane >> 4) * 8;
  f32x4 zero = {0.f, 0.f, 0.f, 0.f};
  f32x4 accR[2][2], accI[2][2];
  #pragma unroll
  for (int m = 0; m < 2; ++m)
    #pragma unroll
    for (int n = 0; n < 2; ++n) { accR[m][n] = zero; accI[m][n] = zero; }
  for (int ks = 0; ks < KLEN / 64; ++ks) {
    const int k0 = ks * 64;
    #pragma unroll
    for (int i = 0; i < 4; ++i) {
      const int r = r0 + i * 16;
      int s0 = xs0[i] + k0;
      float4 xv;
      if (s0 >= 0 && s0 + 3 < L_IN) {
        xv = *(const float4*)&input[xbase[i] + s0];
      } else {
        float ee[4];
        #pragma unroll
        for (int q = 0; q < 4; ++q) {
          int s = s0 + q;
          s = s < 0 ? -s : s;
          s = s >= L_IN ? (2 * L_IN - 2 - s) : s;
          ee[q] = input[xbase[i] + s];
        }
        xv.x = ee[0]; xv.y = ee[1]; xv.z = ee[2]; xv.w = ee[3];
      }
      *(unsigned long long*)&sX[r][kg * 4] = pack4(xv);
      float4 rv = *(const float4*)(bR[i] + k0);
      *(unsigned long long*)&sR[r][kg * 4] = pack4(rv);
      float4 iv = *(const float4*)(bI[i] + k0);
      *(unsigned long long*)&sI[r][kg * 4] = pack4(iv);
    }
    __syncthreads();
    #pragma unroll
    for (int kk = 0; kk < 2; ++kk) {
      const int k = kk * 32 + koff;
      short8 a0 = *(const short8*)&sR[wrow + lr][k];
      short8 a1 = *(const short8*)&sR[wrow + 16 + lr][k];
      short8 c0 = *(const short8*)&sI[wrow + lr][k];
      short8 c1 = *(const short8*)&sI[wrow + 16 + lr][k];
      short8 b0 = *(const short8*)&sX[wcol + lr][k];
      short8 b1 = *(const short8*)&sX[wcol + 16 + lr][k];
      accR[0][0] = __builtin_amdgcn_mfma_f32_16x16x32_bf16(a0, b0, accR[0][0], 0, 0, 0);
      accR[0][1] = __builtin_amdgcn_mfma_f32_16x16x32_bf16(a0, b1, accR[0][1], 0, 0, 0);
      accR[1][0] = __builtin_amdgcn_mfma_f32_16x16x32_bf16(a1, b0, accR[1][0], 0, 0, 0);
      accR[1][1] = __builtin_amdgcn_mfma_f32_16x16x32_bf16(a1, b1, accR[1][1], 0, 0, 0);
      accI[0][0] = __builtin_amdgcn_mfma_f32_16x16x32_bf16(c0, b0, accI[0][0], 0, 0, 0);
      accI[0][1] = __builtin_amdgcn_mfma_f32_16x16x32_bf16(c0, b1, accI[0][1], 0, 0, 0);
      accI[1][0] = __builtin_amdgcn_mfma_f32_16x16x32_bf16(c1, b0, accI[1][0], 0, 0, 0);
      accI[1][1] = __builtin_amdgcn_mfma_f32_16x16x32_bf16(c1, b1, accI[1][1], 0, 0, 0);
    }
    __syncthreads();
  }
  #pragma unroll
  for (int n = 0; n < 2; ++n) {
    int frame = frameBase + wcol + n * 16 + lr;
    if (frame >= NFR) continue;
    unsigned int bb = (unsigned int)frame / 2049u;
    int t = frame - (int)(bb * 2049u);
    long obase = (long)bb * NBINS * T_FR + t;
    #pragma unroll
    for (int m = 0; m < 2; ++m) {
      int binB = binBase + wrow + m * 16 + (lane >> 4) * 4;
      #pragma unroll
      for (int j = 0; j < 4; ++j) {
        int bin = binB + j;
        if (bin < NBINS) {
          float re = accR[m][n][j];
          float im = accI[m][n][j];
          out[obase + (long)bin * T_FR] = sqrtf(re * re + im * im);
        }
      }
    }
  }
}

extern "C" void kernel_launch(void* const* d_in, const int* in_sizes, int n_in,
                              void* d_out, int out_size, void* d_ws, size_t ws_size,
                              hipStream_t stream) {
  const float* input = (const float*)d_in[0];
  const float* basis = (const float*)d_in[1];
  float* out = (float*)d_out;

  const size_t xBytes = (size_t)NBATCH * XWORDS * 2;        // 33,587,200
  const size_t bBytes = (size_t)BROWS2 * KLEN * 2;          // 2,097,152
  const size_t guard  = 262144;                             // tail-iter overread slack
  if (ws_size >= xBytes + bBytes + guard) {
    unsigned short* Xb = (unsigned short*)d_ws;
    unsigned short* Bb = Xb + (size_t)NBATCH * XWORDS;
    prep_x<<<dim3(1025, 16), 256, 0, stream>>>(input, Xb);
    prep_basis2<<<dim3(BROWS2), 256, 0, stream>>>(basis, Bb);
    stft_main<<<dim3(NWG), 512, 0, stream>>>(Xb, Bb, out);
    stft_tail<<<dim3(9, 16), 256, 0, stream>>>(Xb, basis, out);
  } else {
    dim3 grid((NFR + FBN - 1) / FBN, (NBINS + FBM - 1) / FBM);
    stft_fallback<<<grid, dim3(256), 0, stream>>>(input, basis, out);
  }
}

// Round 6
// 110.877 us; speedup vs baseline: 1.0678x; 1.0348x over previous
//
#include <hip/hip_runtime.h>
#include <hip/hip_bf16.h>
#include <math.h>

#define L_IN   1048576
#define NBATCH 16
#define T_FR   2049                 // frames per batch
#define NFR    (NBATCH*T_FR)        // 32784 total frames
#define NBINS  513
#define KLEN   1024
#define HOP    512
#define PADL   512

#define XWORDS 1049600              // padded samples per batch (L_IN + 1024)
#define BROWS2 1024                 // packed basis rows (512 pairs, pair0 = {bin0R, bin512R})

#define BM 256
#define BN 256
#define BK 64

#define NTX 128                     // frame tiles (256 each) -> frames 0..32767
#define NTY 4                       // basis-row tiles (256 each)
#define NWG (NTX*NTY)               // 512 == 2 x 256 CUs exactly

typedef __attribute__((ext_vector_type(8))) short short8;
typedef __attribute__((ext_vector_type(4))) float f32x4;

static __device__ __forceinline__ unsigned short f2bf(float f) {
  unsigned int u = __builtin_bit_cast(unsigned int, f);
  u += 0x7FFFu + ((u >> 16) & 1u);   // RNE
  return (unsigned short)(u >> 16);
}

static __device__ __forceinline__ unsigned long long pack4(float4 v) {
  return (unsigned long long)f2bf(v.x)
       | ((unsigned long long)f2bf(v.y) << 16)
       | ((unsigned long long)f2bf(v.z) << 32)
       | ((unsigned long long)f2bf(v.w) << 48);
}

#define GLOAD_LDS16(gsrc, ldst) \
  __builtin_amdgcn_global_load_lds((const __attribute__((address_space(1))) void*)(gsrc), \
                                   (__attribute__((address_space(3))) void*)(ldst), 16, 0, 0)

// ---------------- prep: basis fp32 -> bf16, packed 1024 rows ----------------
// row r: p=r>>1, s=r&1.  p==0: {real bin0, real bin512}; p>=1: {real p, imag p}.
__global__ void prep_basis2(const float* __restrict__ basis, unsigned short* __restrict__ Bb) {
  const int row = blockIdx.x;          // 0..1023
  const int p = row >> 1, s = row & 1;
  const int src = (p == 0) ? (s ? 512 : 0) : (s ? (513 + p) : p);
  float4 x = *(const float4*)&basis[(long)src * KLEN + threadIdx.x * 4];
  *(unsigned long long*)(Bb + (long)row * KLEN + threadIdx.x * 4) = pack4(x);
}

// ---------------- prep: reflect-padded input fp32 -> bf16, X[16][1049600] ----------------
__global__ void prep_x(const float* __restrict__ input, unsigned short* __restrict__ Xb) {
  const int b  = blockIdx.y;
  const int j0 = blockIdx.x * 1024 + threadIdx.x * 4;   // 1025*1024 == 1049600 exactly
  const int s0 = j0 - PADL;
  float4 x;
  if (s0 >= 0 && s0 + 3 < L_IN) {
    x = *(const float4*)&input[(long)b * L_IN + s0];
  } else {
    float e[4];
    #pragma unroll
    for (int q = 0; q < 4; ++q) {
      int s = s0 + q;
      s = s < 0 ? -s : s;
      s = s >= L_IN ? (2 * L_IN - 2 - s) : s;
      e[q] = input[(long)b * L_IN + s];
    }
    x.x = e[0]; x.y = e[1]; x.z = e[2]; x.w = e[3];
  }
  *(unsigned long long*)(Xb + (long)b * XWORDS + j0) = pack4(x);
}

// ---------------- tail: last 16 frames (batch 15, t=2033..2048), fp32 direct ----------------
__global__ void stft_tail(const unsigned short* __restrict__ Xb,
                          const float* __restrict__ basis,
                          float* __restrict__ out) {
  __shared__ float xs[KLEN];
  __shared__ float sred[57][4];
  const int fi = blockIdx.y;          // 0..15
  const int t  = 2033 + fi;
  const int bt = blockIdx.x;          // 0..8
  const int tid = threadIdx.x;
  const unsigned short* xw = Xb + (long)15 * XWORDS + t * HOP;
  for (int i = tid; i < KLEN; i += 256) {
    unsigned int u = (unsigned int)xw[i] << 16;
    xs[i] = __builtin_bit_cast(float, u);
  }
  __syncthreads();
  const int bi = tid >> 2;            // 0..63
  const int q  = tid & 3;             // bit0 = k-half, bit1 = re/im
  const int bin = bt * 57 + bi;
  if (bi < 57 && bin < NBINS) {
    const int row = (q >> 1) ? (513 + bin) : bin;
    const int k0 = (q & 1) * 512;
    const float* br = basis + (long)row * KLEN + k0;
    float s = 0.f;
    for (int i = 0; i < 512; i += 4) {
      float4 v = *(const float4*)&br[i];
      s += v.x * xs[k0 + i] + v.y * xs[k0 + i + 1] + v.z * xs[k0 + i + 2] + v.w * xs[k0 + i + 3];
    }
    sred[bi][q] = s;
  }
  __syncthreads();
  if (bi < 57 && bin < NBINS && q == 0) {
    float re = sred[bi][0] + sred[bi][1];
    float im = sred[bi][2] + sred[bi][3];
    out[(long)15 * NBINS * T_FR + (long)bin * T_FR + t] = sqrtf(re * re + im * im);
  }
}

// ---------------- main: 256x256x64, 8 waves (2Mx4N, 128x64 each), fully-unrolled 4-phase/K-tile
// Single raw barrier per phase; compiler fine-grained auto-waitcnt for ds_read->MFMA;
// counted vmcnt(4) once per K-tile; all LDS/global offsets compile-time immediates.
__global__ __launch_bounds__(512, 2)
void stft_main(const unsigned short* __restrict__ Xb,
               const unsigned short* __restrict__ Bb,
               float* __restrict__ out)
{
  __shared__ unsigned short sA[2][256][64];   // [parity][row][k]   64 KB
  __shared__ unsigned short sB[2][256][64];   // [parity][frame][k] 64 KB

  const int tid  = threadIdx.x;
  const int lane = tid & 63;
  const int w    = tid >> 6;               // wave 0..7

  // ---- XCD swizzle: NWG=512 -> wg = xcd*64 + idx (bijective); y-fast for Xb slab reuse ----
  const int bid = blockIdx.x;
  const int wg  = (bid & 7) * 64 + (bid >> 3);
  const int frameBase = (wg >> 2) * BN;    // tileX = wg/4
  const int rowBase   = (wg & 3) * BM;     // tileY = wg%4

  // ---- staging pointers: half h, instr i covers rows h*128 + i*64 + w*8 + (lane>>3) ----
  const int lr8 = lane >> 3;               // row within 8-row group (== row&7)
  const int lc8 = lane & 7;                // physical 16B chunk
  const int cs  = (lc8 ^ lr8) * 8;         // inverse-swizzled source offset (shorts)

  const unsigned short* aPtr[4];
  const unsigned short* bPtr[4];
  #pragma unroll
  for (int hi = 0; hi < 4; ++hi) {
    const int h = hi >> 1, i = hi & 1;
    const int r = h * 128 + i * 64 + w * 8 + lr8;
    aPtr[hi] = Bb + (long)(rowBase + r) * KLEN + cs;
    const int frame = frameBase + r;       // <= 32767, always valid
    const int bb = frame / T_FR;
    const int t  = frame - bb * T_FR;
    bPtr[hi] = Xb + (long)bb * XWORDS + t * HOP + cs;
  }

  const int lr = lane & 15;
  const int ql = lane >> 4;                // 0..3
  const int e8 = lr & 7;                   // fragment row & 7
  const int wr = (w >> 2) * 128;           // wave's basis-row offset (2 M-halves)
  const int wc = (w & 3) * 64;             // wave's frame offset (4 N-quarters)
  const int c0 = ((ql)     ^ e8) * 8;      // swizzled chunk offset, k-slot 0
  const int c1 = ((4 + ql) ^ e8) * 8;      // k-slot 1

  f32x4 acc[8][4];
  #pragma unroll
  for (int m = 0; m < 8; ++m)
    #pragma unroll
    for (int n = 0; n < 4; ++n) acc[m][n] = (f32x4){0.f, 0.f, 0.f, 0.f};

  short8 bf[4][2];                          // B-frags, live across the 4 phases of a K-tile

  #define SA(par, h, koff) do {                                              \
    GLOAD_LDS16(aPtr[(h)*2]     + (koff), &sA[par][(h)*128      + w*8][0]);  \
    GLOAD_LDS16(aPtr[(h)*2 + 1] + (koff), &sA[par][(h)*128 + 64 + w*8][0]);  \
  } while (0)
  #define SB(par, h, koff) do {                                              \
    GLOAD_LDS16(bPtr[(h)*2]     + (koff), &sB[par][(h)*128      + w*8][0]);  \
    GLOAD_LDS16(bPtr[(h)*2 + 1] + (koff), &sB[par][(h)*128 + 64 + w*8][0]);  \
  } while (0)

  #define VM4  asm volatile("s_waitcnt vmcnt(4)" ::: "memory")
  #define VM0  asm volatile("s_waitcnt vmcnt(0)" ::: "memory")
  #define BAR  asm volatile("s_barrier" ::: "memory")
  #define NOPS ((void)0)

  // one phase: [B-frag reads if q0] + A-quad reads + stage + 16 MFMA + [vm join] + barrier.
  // Every read feeds a same-phase MFMA -> auto-waitcnt completes it before the barrier,
  // so the single trailing barrier is sufficient for the WAR on buffers staged next phases.
  #define PHASE(par, q, READB, SS, VM) do {                                  \
    if (READB) {                                                             \
      _Pragma("unroll")                                                      \
      for (int n = 0; n < 4; ++n) {                                          \
        bf[n][0] = *(const short8*)&sB[par][wc + n * 16 + lr][c0];           \
        bf[n][1] = *(const short8*)&sB[par][wc + n * 16 + lr][c1];           \
      }                                                                      \
    }                                                                        \
    short8 aq[2][2];                                                         \
    aq[0][0] = *(const short8*)&sA[par][wr + (2*(q))     * 16 + lr][c0];     \
    aq[0][1] = *(const short8*)&sA[par][wr + (2*(q))     * 16 + lr][c1];     \
    aq[1][0] = *(const short8*)&sA[par][wr + (2*(q) + 1) * 16 + lr][c0];     \
    aq[1][1] = *(const short8*)&sA[par][wr + (2*(q) + 1) * 16 + lr][c1];     \
    SS;                                                                      \
    __builtin_amdgcn_s_setprio(1);                                           \
    _Pragma("unroll")                                                        \
    for (int mi = 0; mi < 2; ++mi)                                           \
      _Pragma("unroll")                                                      \
      for (int n = 0; n < 4; ++n)                                            \
        _Pragma("unroll")                                                    \
        for (int k = 0; k < 2; ++k)                                          \
          acc[2*(q) + mi][n] =                                               \
            __builtin_amdgcn_mfma_f32_16x16x32_bf16(aq[mi][k], bf[n][k],     \
                                                    acc[2*(q) + mi][n], 0, 0, 0); \
    __builtin_amdgcn_s_setprio(0);                                           \
    VM;                                                                      \
    BAR;                                                                     \
  } while (0)

  // K-tile t (parity par): reads par; stages A(t+1)->sA[par^1] (ph0-1), B(t+2)->sB[par] (ph2-3).
  // vmcnt(4) at tile end retires A(t+1)+B(t+1) (B(t+2) stays in flight).
  #define TILE(t, par) do {                                                  \
    PHASE(par, 0, 1, SA((par)^1, 0, (t+1)*64), NOPS);                        \
    PHASE(par, 1, 0, SA((par)^1, 1, (t+1)*64), NOPS);                        \
    PHASE(par, 2, 0, SB(par,     0, (t+2)*64), NOPS);                        \
    PHASE(par, 3, 0, SB(par,     1, (t+2)*64), VM4);                         \
  } while (0)

  // ---- prologue: tile0 A+B (8 gloads) + B(1) (4 gloads); join tile0, carry B(1) ----
  SB(0, 0, 0);  SB(0, 1, 0);
  SA(0, 0, 0);  SA(0, 1, 0);
  SB(1, 0, 64); SB(1, 1, 64);
  VM4;
  BAR;

  // ---- fully-unrolled K loop: 16 tiles, all offsets immediate ----
  TILE(0, 0);  TILE(1, 1);  TILE(2, 0);  TILE(3, 1);
  TILE(4, 0);  TILE(5, 1);  TILE(6, 0);  TILE(7, 1);
  TILE(8, 0);  TILE(9, 1);  TILE(10, 0); TILE(11, 1);
  TILE(12, 0); TILE(13, 1);
  // tile 14 (par 0): stage A(15) only; drain all loads at end
  PHASE(0, 0, 1, SA(1, 0, 15*64), NOPS);
  PHASE(0, 1, 0, SA(1, 1, 15*64), NOPS);
  PHASE(0, 2, 0, NOPS, NOPS);
  PHASE(0, 3, 0, NOPS, VM0);
  // tile 15 (par 1): no staging
  PHASE(1, 0, 1, NOPS, NOPS);
  PHASE(1, 1, 0, NOPS, NOPS);
  PHASE(1, 2, 0, NOPS, NOPS);
  PHASE(1, 3, 0, NOPS, NOPS);

  #undef TILE
  #undef PHASE
  #undef SA
  #undef SB
  #undef VM4
  #undef VM0
  #undef BAR
  #undef NOPS

  // ---- epilogue: pairs {R,I} lane-local; pair0 = {bin0, bin512} -> plain |.| ----
  #pragma unroll
  for (int n = 0; n < 4; ++n) {
    const int frame = frameBase + wc + n * 16 + lr;   // < 32768 always
    const int bb = frame / T_FR;
    const int t  = frame - bb * T_FR;
    const long ob = (long)bb * NBINS * T_FR + t;
    #pragma unroll
    for (int m = 0; m < 8; ++m) {
      const int grow = rowBase + wr + m * 16 + ql * 4;  // multiple of 4
      const int p0 = grow >> 1;                          // even pair index
      const float x0 = acc[m][n][0], x1 = acc[m][n][1];
      const float x2 = acc[m][n][2], x3 = acc[m][n][3];
      if (p0 == 0) {
        out[ob]                    = fabsf(x0);          // bin 0
        out[ob + (long)512 * T_FR] = fabsf(x1);          // bin 512
      } else {
        out[ob + (long)p0 * T_FR] = sqrtf(x0 * x0 + x1 * x1);
      }
      out[ob + (long)(p0 + 1) * T_FR] = sqrtf(x2 * x2 + x3 * x3);  // bins 1..511
    }
  }
}

// ---------------- fallback (round-1 kernel) if ws is too small ----------------
#define FBM 64
#define FBN 64
#define FPITCH 72
__global__ __launch_bounds__(256, 2)
void stft_fallback(const float* __restrict__ input,
                   const float* __restrict__ basis,
                   float* __restrict__ out)
{
  __shared__ unsigned short sX[FBN][FPITCH];
  __shared__ unsigned short sR[FBM][FPITCH];
  __shared__ unsigned short sI[FBM][FPITCH];
  const int tid = threadIdx.x;
  const int frameBase = blockIdx.x * FBN;
  const int binBase   = blockIdx.y * FBM;
  const int r0 = tid >> 4;
  const int kg = tid & 15;
  long xbase[4]; int xs0[4];
  const float* bR[4]; const float* bI[4];
  #pragma unroll
  for (int i = 0; i < 4; ++i) {
    int r = r0 + i * 16;
    int frame = frameBase + r;
    int fcl = frame < NFR ? frame : (NFR - 1);
    unsigned int bb = (unsigned int)fcl / 2049u;
    int t = fcl - (int)(bb * 2049u);
    xbase[i] = (long)bb * L_IN;
    xs0[i]   = t * HOP - PADL + kg * 4;
    int bin = binBase + r;
    int rr = bin < 512 ? bin : 512;
    int ri = bin + 513; ri = ri < 1025 ? ri : 1025;
    bR[i] = basis + (long)rr * KLEN + kg * 4;
    bI[i] = basis + (long)ri * KLEN + kg * 4;
  }
  const int lane = tid & 63;
  const int wid  = tid >> 6;
  const int wrow = (wid >> 1) * 32;
  const int wcol = (wid & 1) * 32;
  const int lr   = lane & 15;
  const int koff = (lane >> 4) * 8;
  f32x4 zero = {0.f, 0.f, 0.f, 0.f};
  f32x4 accR[2][2], accI[2][2];
  #pragma unroll
  for (int m = 0; m < 2; ++m)
    #pragma unroll
    for (int n = 0; n < 2; ++n) { accR[m][n] = zero; accI[m][n] = zero; }
  for (int ks = 0; ks < KLEN / 64; ++ks) {
    const int k0 = ks * 64;
    #pragma unroll
    for (int i = 0; i < 4; ++i) {
      const int r = r0 + i * 16;
      int s0 = xs0[i] + k0;
      float4 xv;
      if (s0 >= 0 && s0 + 3 < L_IN) {
        xv = *(const float4*)&input[xbase[i] + s0];
      } else {
        float ee[4];
        #pragma unroll
        for (int q = 0; q < 4; ++q) {
          int s = s0 + q;
          s = s < 0 ? -s : s;
          s = s >= L_IN ? (2 * L_IN - 2 - s) : s;
          ee[q] = input[xbase[i] + s];
        }
        xv.x = ee[0]; xv.y = ee[1]; xv.z = ee[2]; xv.w = ee[3];
      }
      *(unsigned long long*)&sX[r][kg * 4] = pack4(xv);
      float4 rv = *(const float4*)(bR[i] + k0);
      *(unsigned long long*)&sR[r][kg * 4] = pack4(rv);
      float4 iv = *(const float4*)(bI[i] + k0);
      *(unsigned long long*)&sI[r][kg * 4] = pack4(iv);
    }
    __syncthreads();
    #pragma unroll
    for (int kk = 0; kk < 2; ++kk) {
      const int k = kk * 32 + koff;
      short8 a0 = *(const short8*)&sR[wrow + lr][k];
      short8 a1 = *(const short8*)&sR[wrow + 16 + lr][k];
      short8 c0 = *(const short8*)&sI[wrow + lr][k];
      short8 c1 = *(const short8*)&sI[wrow + 16 + lr][k];
      short8 b0 = *(const short8*)&sX[wcol + lr][k];
      short8 b1 = *(const short8*)&sX[wcol + 16 + lr][k];
      accR[0][0] = __builtin_amdgcn_mfma_f32_16x16x32_bf16(a0, b0, accR[0][0], 0, 0, 0);
      accR[0][1] = __builtin_amdgcn_mfma_f32_16x16x32_bf16(a0, b1, accR[0][1], 0, 0, 0);
      accR[1][0] = __builtin_amdgcn_mfma_f32_16x16x32_bf16(a1, b0, accR[1][0], 0, 0, 0);
      accR[1][1] = __builtin_amdgcn_mfma_f32_16x16x32_bf16(a1, b1, accR[1][1], 0, 0, 0);
      accI[0][0] = __builtin_amdgcn_mfma_f32_16x16x32_bf16(c0, b0, accI[0][0], 0, 0, 0);
      accI[0][1] = __builtin_amdgcn_mfma_f32_16x16x32_bf16(c0, b1, accI[0][1], 0, 0, 0);
      accI[1][0] = __builtin_amdgcn_mfma_f32_16x16x32_bf16(c1, b0, accI[1][0], 0, 0, 0);
      accI[1][1] = __builtin_amdgcn_mfma_f32_16x16x32_bf16(c1, b1, accI[1][1], 0, 0, 0);
    }
    __syncthreads();
  }
  #pragma unroll
  for (int n = 0; n < 2; ++n) {
    int frame = frameBase + wcol + n * 16 + lr;
    if (frame >= NFR) continue;
    unsigned int bb = (unsigned int)frame / 2049u;
    int t = frame - (int)(bb * 2049u);
    long obase = (long)bb * NBINS * T_FR + t;
    #pragma unroll
    for (int m = 0; m < 2; ++m) {
      int binB = binBase + wrow + m * 16 + (lane >> 4) * 4;
      #pragma unroll
      for (int j = 0; j < 4; ++j) {
        int bin = binB + j;
        if (bin < NBINS) {
          float re = accR[m][n][j];
          float im = accI[m][n][j];
          out[obase + (long)bin * T_FR] = sqrtf(re * re + im * im);
        }
      }
    }
  }
}

extern "C" void kernel_launch(void* const* d_in, const int* in_sizes, int n_in,
                              void* d_out, int out_size, void* d_ws, size_t ws_size,
                              hipStream_t stream) {
  const float* input = (const float*)d_in[0];
  const float* basis = (const float*)d_in[1];
  float* out = (float*)d_out;

  const size_t xBytes = (size_t)NBATCH * XWORDS * 2;        // 33,587,200
  const size_t bBytes = (size_t)BROWS2 * KLEN * 2;          // 2,097,152
  const size_t guard  = 262144;
  if (ws_size >= xBytes + bBytes + guard) {
    unsigned short* Xb = (unsigned short*)d_ws;
    unsigned short* Bb = Xb + (size_t)NBATCH * XWORDS;
    prep_x<<<dim3(1025, 16), 256, 0, stream>>>(input, Xb);
    prep_basis2<<<dim3(BROWS2), 256, 0, stream>>>(basis, Bb);
    stft_main<<<dim3(NWG), 512, 0, stream>>>(Xb, Bb, out);
    stft_tail<<<dim3(9, 16), 256, 0, stream>>>(Xb, basis, out);
  } else {
    dim3 grid((NFR + FBN - 1) / FBN, (NBINS + FBM - 1) / FBM);
    stft_fallback<<<grid, dim3(256), 0, stream>>>(input, basis, out);
  }
}

// Round 7
// 110.246 us; speedup vs baseline: 1.0739x; 1.0057x over previous
//
#include <hip/hip_runtime.h>
#include <hip/hip_bf16.h>
#include <math.h>

#define L_IN   1048576
#define NBATCH 16
#define T_FR   2049                 // frames per batch
#define NFR    (NBATCH*T_FR)        // 32784 total frames
#define NBINS  513
#define KLEN   1024
#define HOP    512
#define PADL   512

#define XWORDS 1049600              // padded samples per batch (L_IN + 1024)
#define BROWS2 1024                 // packed basis rows (512 pairs, pair0 = {bin0R, bin512R})

#define BM 128
#define BN 128
#define BK 64
#define NKT (KLEN/BK)               // 16

#define NTY 8                       // M tiles (128 each) -> 1024 rows
#define NTX 256                     // frame tiles (128 each) -> frames 0..32767
#define NWG (NTX*NTY)               // 2048 = 8 XCDs x 256

typedef __attribute__((ext_vector_type(8))) short short8;
typedef __attribute__((ext_vector_type(4))) float f32x4;

static __device__ __forceinline__ unsigned short f2bf(float f) {
  unsigned int u = __builtin_bit_cast(unsigned int, f);
  u += 0x7FFFu + ((u >> 16) & 1u);   // RNE
  return (unsigned short)(u >> 16);
}

static __device__ __forceinline__ unsigned long long pack4(float4 v) {
  return (unsigned long long)f2bf(v.x)
       | ((unsigned long long)f2bf(v.y) << 16)
       | ((unsigned long long)f2bf(v.z) << 32)
       | ((unsigned long long)f2bf(v.w) << 48);
}

#define GLOAD_LDS16(gsrc, ldst) \
  __builtin_amdgcn_global_load_lds((const __attribute__((address_space(1))) void*)(gsrc), \
                                   (__attribute__((address_space(3))) void*)(ldst), 16, 0, 0)

// ---------------- prep: basis fp32 -> bf16, packed 1024 rows ----------------
// row r: p=r>>1, s=r&1.  p==0: {real bin0, real bin512}; p>=1: {real p, imag p}.
__global__ void prep_basis2(const float* __restrict__ basis, unsigned short* __restrict__ Bb) {
  const int row = blockIdx.x;          // 0..1023
  const int p = row >> 1, s = row & 1;
  const int src = (p == 0) ? (s ? 512 : 0) : (s ? (513 + p) : p);
  float4 x = *(const float4*)&basis[(long)src * KLEN + threadIdx.x * 4];
  *(unsigned long long*)(Bb + (long)row * KLEN + threadIdx.x * 4) = pack4(x);
}

// ---------------- prep: reflect-padded input fp32 -> bf16, X[16][1049600] ----------------
__global__ void prep_x(const float* __restrict__ input, unsigned short* __restrict__ Xb) {
  const int b  = blockIdx.y;
  const int j0 = blockIdx.x * 1024 + threadIdx.x * 4;   // 1025*1024 == 1049600 exactly
  const int s0 = j0 - PADL;
  float4 x;
  if (s0 >= 0 && s0 + 3 < L_IN) {
    x = *(const float4*)&input[(long)b * L_IN + s0];
  } else {
    float e[4];
    #pragma unroll
    for (int q = 0; q < 4; ++q) {
      int s = s0 + q;
      s = s < 0 ? -s : s;
      s = s >= L_IN ? (2 * L_IN - 2 - s) : s;
      e[q] = input[(long)b * L_IN + s];
    }
    x.x = e[0]; x.y = e[1]; x.z = e[2]; x.w = e[3];
  }
  *(unsigned long long*)(Xb + (long)b * XWORDS + j0) = pack4(x);
}

// ---------------- tail: last 16 frames (batch 15, t=2033..2048), fp32 direct ----------------
__global__ void stft_tail(const unsigned short* __restrict__ Xb,
                          const float* __restrict__ basis,
                          float* __restrict__ out) {
  __shared__ float xs[KLEN];
  __shared__ float sred[57][4];
  const int fi = blockIdx.y;          // 0..15
  const int t  = 2033 + fi;
  const int bt = blockIdx.x;          // 0..8
  const int tid = threadIdx.x;
  const unsigned short* xw = Xb + (long)15 * XWORDS + t * HOP;
  for (int i = tid; i < KLEN; i += 256) {
    unsigned int u = (unsigned int)xw[i] << 16;
    xs[i] = __builtin_bit_cast(float, u);
  }
  __syncthreads();
  const int bi = tid >> 2;            // 0..63
  const int q  = tid & 3;             // bit0 = k-half, bit1 = re/im
  const int bin = bt * 57 + bi;
  if (bi < 57 && bin < NBINS) {
    const int row = (q >> 1) ? (513 + bin) : bin;
    const int k0 = (q & 1) * 512;
    const float* br = basis + (long)row * KLEN + k0;
    float s = 0.f;
    for (int i = 0; i < 512; i += 4) {
      float4 v = *(const float4*)&br[i];
      s += v.x * xs[k0 + i] + v.y * xs[k0 + i + 1] + v.z * xs[k0 + i + 2] + v.w * xs[k0 + i + 3];
    }
    sred[bi][q] = s;
  }
  __syncthreads();
  if (bi < 57 && bin < NBINS && q == 0) {
    float re = sred[bi][0] + sred[bi][1];
    float im = sred[bi][2] + sred[bi][3];
    out[(long)15 * NBINS * T_FR + (long)bin * T_FR + t] = sqrtf(re * re + im * im);
  }
}

// ---------------- main: m97 structure. 128x128x64, 4 waves (2x2, 64x64 each),
// single-buffered 32 KB LDS, {stage, sync, compute, sync} K-loop, 3 blocks/CU.
__global__ __launch_bounds__(256, 3)
void stft_main(const unsigned short* __restrict__ Xb,
               const unsigned short* __restrict__ Bb,
               float* __restrict__ out)
{
  __shared__ unsigned short sA[128][64];   // 16 KB basis rows
  __shared__ unsigned short sB[128][64];   // 16 KB frames

  const int tid  = threadIdx.x;
  const int lane = tid & 63;
  const int w    = tid >> 6;               // wave 0..3

  // ---- XCD swizzle: NWG=2048 -> wg = xcd*256 + idx (bijective).
  // y-fast: wg&7 = M-tile (8 consecutive wg share a frame slab + walk whole basis)
  const int bid = blockIdx.x;
  const int wg  = (bid & 7) * 256 + (bid >> 3);
  const int rowBase   = (wg & 7) * BM;
  const int frameBase = (wg >> 3) * BN;

  // ---- staging: wave w covers rows w*32 + q*8 + (lane>>3), 16B chunk lane&7 ----
  const int lr8 = lane >> 3;               // row within 8-row group (== row&7)
  const int lc8 = lane & 7;                // physical 16B chunk
  const int cs  = (lc8 ^ lr8) * 8;         // inverse-swizzled source offset (shorts)

  const unsigned short* aP[4];
  const unsigned short* bP[4];
  #pragma unroll
  for (int q = 0; q < 4; ++q) {
    const int r = w * 32 + q * 8 + lr8;
    aP[q] = Bb + (long)(rowBase + r) * KLEN + cs;
    const int frame = frameBase + r;       // <= 32767, always valid
    const int bb = frame / T_FR;
    const int t  = frame - bb * T_FR;
    bP[q] = Xb + (long)bb * XWORDS + t * HOP + cs;
  }

  const int lr = lane & 15;
  const int ql = lane >> 4;                // 0..3
  const int e8 = lr & 7;                   // fragment row & 7
  const int wr = (w >> 1) * 64;            // wave's basis-row offset in tile
  const int wc = (w & 1) * 64;             // wave's frame offset in tile
  const int c0 = ((ql)     ^ e8) * 8;      // swizzled chunk offset, k-slot 0
  const int c1 = ((4 + ql) ^ e8) * 8;      // k-slot 1

  f32x4 acc[4][4];
  #pragma unroll
  for (int m = 0; m < 4; ++m)
    #pragma unroll
    for (int n = 0; n < 4; ++n) acc[m][n] = (f32x4){0.f, 0.f, 0.f, 0.f};

  for (int ks = 0; ks < NKT; ++ks) {
    // ---- stage (8 x global_load_lds dwordx4 per wave) ----
    #pragma unroll
    for (int q = 0; q < 4; ++q) {
      GLOAD_LDS16(aP[q], &sA[w * 32 + q * 8][0]);  aP[q] += BK;
      GLOAD_LDS16(bP[q], &sB[w * 32 + q * 8][0]);  bP[q] += BK;
    }
    __syncthreads();
    // ---- compute: 2 k-slots x 16 MFMA ----
    #pragma unroll
    for (int kk = 0; kk < 2; ++kk) {
      const int c = kk ? c1 : c0;
      short8 a[4], b[4];
      #pragma unroll
      for (int m = 0; m < 4; ++m) a[m] = *(const short8*)&sA[wr + m * 16 + lr][c];
      #pragma unroll
      for (int n = 0; n < 4; ++n) b[n] = *(const short8*)&sB[wc + n * 16 + lr][c];
      #pragma unroll
      for (int m = 0; m < 4; ++m)
        #pragma unroll
        for (int n = 0; n < 4; ++n)
          acc[m][n] = __builtin_amdgcn_mfma_f32_16x16x32_bf16(a[m], b[n], acc[m][n], 0, 0, 0);
    }
    __syncthreads();
  }

  // ---- epilogue: pairs {R,I} lane-local; pair0 = {bin0, bin512} -> plain |.| ----
  #pragma unroll
  for (int n = 0; n < 4; ++n) {
    const int frame = frameBase + wc + n * 16 + lr;   // < 32768 always
    const int bb = frame / T_FR;
    const int t  = frame - bb * T_FR;
    const long ob = (long)bb * NBINS * T_FR + t;
    #pragma unroll
    for (int m = 0; m < 4; ++m) {
      const int grow = rowBase + wr + m * 16 + ql * 4;  // multiple of 4
      const int p0 = grow >> 1;                          // even pair index
      const float x0 = acc[m][n][0], x1 = acc[m][n][1];
      const float x2 = acc[m][n][2], x3 = acc[m][n][3];
      if (p0 == 0) {
        out[ob]                    = fabsf(x0);          // bin 0
        out[ob + (long)512 * T_FR] = fabsf(x1);          // bin 512
      } else {
        out[ob + (long)p0 * T_FR] = sqrtf(x0 * x0 + x1 * x1);
      }
      out[ob + (long)(p0 + 1) * T_FR] = sqrtf(x2 * x2 + x3 * x3);  // bins 1..511
    }
  }
}

// ---------------- fallback (round-1 kernel) if ws is too small ----------------
#define FBM 64
#define FBN 64
#define FPITCH 72
__global__ __launch_bounds__(256, 2)
void stft_fallback(const float* __restrict__ input,
                   const float* __restrict__ basis,
                   float* __restrict__ out)
{
  __shared__ unsigned short sX[FBN][FPITCH];
  __shared__ unsigned short sR[FBM][FPITCH];
  __shared__ unsigned short sI[FBM][FPITCH];
  const int tid = threadIdx.x;
  const int frameBase = blockIdx.x * FBN;
  const int binBase   = blockIdx.y * FBM;
  const int r0 = tid >> 4;
  const int kg = tid & 15;
  long xbase[4]; int xs0[4];
  const float* bR[4]; const float* bI[4];
  #pragma unroll
  for (int i = 0; i < 4; ++i) {
    int r = r0 + i * 16;
    int frame = frameBase + r;
    int fcl = frame < NFR ? frame : (NFR - 1);
    unsigned int bb = (unsigned int)fcl / 2049u;
    int t = fcl - (int)(bb * 2049u);
    xbase[i] = (long)bb * L_IN;
    xs0[i]   = t * HOP - PADL + kg * 4;
    int bin = binBase + r;
    int rr = bin < 512 ? bin : 512;
    int ri = bin + 513; ri = ri < 1025 ? ri : 1025;
    bR[i] = basis + (long)rr * KLEN + kg * 4;
    bI[i] = basis + (long)ri * KLEN + kg * 4;
  }
  const int lane = tid & 63;
  const int wid  = tid >> 6;
  const int wrow = (wid >> 1) * 32;
  const int wcol = (wid & 1) * 32;
  const int lr   = lane & 15;
  const int koff = (lane >> 4) * 8;
  f32x4 zero = {0.f, 0.f, 0.f, 0.f};
  f32x4 accR[2][2], accI[2][2];
  #pragma unroll
  for (int m = 0; m < 2; ++m)
    #pragma unroll
    for (int n = 0; n < 2; ++n) { accR[m][n] = zero; accI[m][n] = zero; }
  for (int ks = 0; ks < KLEN / 64; ++ks) {
    const int k0 = ks * 64;
    #pragma unroll
    for (int i = 0; i < 4; ++i) {
      const int r = r0 + i * 16;
      int s0 = xs0[i] + k0;
      float4 xv;
      if (s0 >= 0 && s0 + 3 < L_IN) {
        xv = *(const float4*)&input[xbase[i] + s0];
      } else {
        float ee[4];
        #pragma unroll
        for (int q = 0; q < 4; ++q) {
          int s = s0 + q;
          s = s < 0 ? -s : s;
          s = s >= L_IN ? (2 * L_IN - 2 - s) : s;
          ee[q] = input[xbase[i] + s];
        }
        xv.x = ee[0]; xv.y = ee[1]; xv.z = ee[2]; xv.w = ee[3];
      }
      *(unsigned long long*)&sX[r][kg * 4] = pack4(xv);
      float4 rv = *(const float4*)(bR[i] + k0);
      *(unsigned long long*)&sR[r][kg * 4] = pack4(rv);
      float4 iv = *(const float4*)(bI[i] + k0);
      *(unsigned long long*)&sI[r][kg * 4] = pack4(iv);
    }
    __syncthreads();
    #pragma unroll
    for (int kk = 0; kk < 2; ++kk) {
      const int k = kk * 32 + koff;
      short8 a0 = *(const short8*)&sR[wrow + lr][k];
      short8 a1 = *(const short8*)&sR[wrow + 16 + lr][k];
      short8 c0 = *(const short8*)&sI[wrow + lr][k];
      short8 c1 = *(const short8*)&sI[wrow + 16 + lr][k];
      short8 b0 = *(const short8*)&sX[wcol + lr][k];
      short8 b1 = *(const short8*)&sX[wcol + 16 + lr][k];
      accR[0][0] = __builtin_amdgcn_mfma_f32_16x16x32_bf16(a0, b0, accR[0][0], 0, 0, 0);
      accR[0][1] = __builtin_amdgcn_mfma_f32_16x16x32_bf16(a0, b1, accR[0][1], 0, 0, 0);
      accR[1][0] = __builtin_amdgcn_mfma_f32_16x16x32_bf16(a1, b0, accR[1][0], 0, 0, 0);
      accR[1][1] = __builtin_amdgcn_mfma_f32_16x16x32_bf16(a1, b1, accR[1][1], 0, 0, 0);
      accI[0][0] = __builtin_amdgcn_mfma_f32_16x16x32_bf16(c0, b0, accI[0][0], 0, 0, 0);
      accI[0][1] = __builtin_amdgcn_mfma_f32_16x16x32_bf16(c0, b1, accI[0][1], 0, 0, 0);
      accI[1][0] = __builtin_amdgcn_mfma_f32_16x16x32_bf16(c1, b0, accI[1][0], 0, 0, 0);
      accI[1][1] = __builtin_amdgcn_mfma_f32_16x16x32_bf16(c1, b1, accI[1][1], 0, 0, 0);
    }
    __syncthreads();
  }
  #pragma unroll
  for (int n = 0; n < 2; ++n) {
    int frame = frameBase + wcol + n * 16 + lr;
    if (frame >= NFR) continue;
    unsigned int bb = (unsigned int)frame / 2049u;
    int t = frame - (int)(bb * 2049u);
    long obase = (long)bb * NBINS * T_FR + t;
    #pragma unroll
    for (int m = 0; m < 2; ++m) {
      int binB = binBase + wrow + m * 16 + (lane >> 4) * 4;
      #pragma unroll
      for (int j = 0; j < 4; ++j) {
        int bin = binB + j;
        if (bin < NBINS) {
          float re = accR[m][n][j];
          float im = accI[m][n][j];
          out[obase + (long)bin * T_FR] = sqrtf(re * re + im * im);
        }
      }
    }
  }
}

extern "C" void kernel_launch(void* const* d_in, const int* in_sizes, int n_in,
                              void* d_out, int out_size, void* d_ws, size_t ws_size,
                              hipStream_t stream) {
  const float* input = (const float*)d_in[0];
  const float* basis = (const float*)d_in[1];
  float* out = (float*)d_out;

  const size_t xBytes = (size_t)NBATCH * XWORDS * 2;        // 33,587,200
  const size_t bBytes = (size_t)BROWS2 * KLEN * 2;          // 2,097,152
  if (ws_size >= xBytes + bBytes) {
    unsigned short* Xb = (unsigned short*)d_ws;
    unsigned short* Bb = Xb + (size_t)NBATCH * XWORDS;
    prep_x<<<dim3(1025, 16), 256, 0, stream>>>(input, Xb);
    prep_basis2<<<dim3(BROWS2), 256, 0, stream>>>(basis, Bb);
    stft_main<<<dim3(NWG), 256, 0, stream>>>(Xb, Bb, out);
    stft_tail<<<dim3(9, 16), 256, 0, stream>>>(Xb, basis, out);
  } else {
    dim3 grid((NFR + FBN - 1) / FBN, (NBINS + FBM - 1) / FBM);
    stft_fallback<<<grid, dim3(256), 0, stream>>>(input, basis, out);
  }
}

// Round 8
// 69.113 us; speedup vs baseline: 1.7130x; 1.5952x over previous
//
#include <hip/hip_runtime.h>
#include <math.h>

#define L_IN   1048576
#define NBATCH 16
#define T_FR   2049
#define NBINS  513

// ---------------- complex helpers ----------------
struct C2 { float r, i; };
__device__ __forceinline__ C2 cadd(C2 a, C2 b){ return {a.r+b.r, a.i+b.i}; }
__device__ __forceinline__ C2 csub(C2 a, C2 b){ return {a.r-b.r, a.i-b.i}; }
__device__ __forceinline__ C2 cmul(C2 a, C2 b){ return {a.r*b.r - a.i*b.i, a.r*b.i + a.i*b.r}; }
__device__ __forceinline__ C2 cnegi(C2 a){ return {a.i, -a.r}; }            // a * (-i)
#define RSQ2 0.70710678118654752f
__device__ __forceinline__ C2 cw8 (C2 a){ return { RSQ2*(a.r+a.i),  RSQ2*(a.i-a.r)}; }  // a * w8  = (1-i)/sqrt2
__device__ __forceinline__ C2 cw83(C2 a){ return { RSQ2*(a.i-a.r), -RSQ2*(a.r+a.i)}; }  // a * w8^3

// 8-point DFT, natural order in/out, w8 = e^{-i pi/4}.
// Verified: impulse at x1 -> y_k = w8^k.
__device__ __forceinline__ void dft8(const C2 x[8], C2 y[8]) {
  C2 ea0 = cadd(x[0], x[4]), ea1 = csub(x[0], x[4]);
  C2 eb0 = cadd(x[2], x[6]), eb1 = csub(x[2], x[6]);
  C2 oa0 = cadd(x[1], x[5]), oa1 = csub(x[1], x[5]);
  C2 ob0 = cadd(x[3], x[7]), ob1 = csub(x[3], x[7]);
  C2 E0 = cadd(ea0, eb0), E2 = csub(ea0, eb0);
  C2 nb = cnegi(eb1);
  C2 E1 = cadd(ea1, nb),  E3 = csub(ea1, nb);
  C2 O0 = cadd(oa0, ob0), O2 = csub(oa0, ob0);
  C2 no = cnegi(ob1);
  C2 O1 = cadd(oa1, no),  O3 = csub(oa1, no);
  y[0] = cadd(E0, O0);  y[4] = csub(E0, O0);
  C2 t1 = cw8(O1);      y[1] = cadd(E1, t1); y[5] = csub(E1, t1);
  C2 t2 = cnegi(O2);    y[2] = cadd(E2, t2); y[6] = csub(E2, t2);
  C2 t3 = cw83(O3);     y[3] = cadd(E3, t3); y[7] = csub(E3, t3);
}

// LDS bank-spread swizzle (bijective on [0,512)): breaks the 16-way/8-way
// conflicts of the strided Stockham writes while keeping stride-1 phases at
// the 4-lane/bank-pair b64 baseline (verified per access pattern).
__device__ __forceinline__ int phys(int idx) { return idx ^ ((idx >> 4) & 15); }

#define FENCE do { asm volatile("s_waitcnt lgkmcnt(0)" ::: "memory"); \
                   __builtin_amdgcn_sched_barrier(0); } while (0)

// One block = 16 consecutive frames of one batch. 4 waves; wave w computes
// frames tl = 4w..4w+3 sequentially, each wave fully independent (no barriers
// inside the FFT: wave64 lockstep + in-order DS pipe + FENCEs).
__global__ __launch_bounds__(256, 2)
void stft_fft(const float* __restrict__ input,
              const float* __restrict__ basis,
              float* __restrict__ out)
{
  __shared__ C2   cf[4][512];      // per-wave FFT exchange array (in-place Stockham)
  __shared__ C2   tw512[512];      // W_512^i, stored at phys(i)
  __shared__ C2   wu[513];         // W_1024^k for real-unpack
  __shared__ float mag[513][17];   // output transpose staging (17 = conflict-free pad)

  const int tid = threadIdx.x;
  const int t   = tid & 63;        // lane
  const int w   = tid >> 6;        // wave 0..3
  const int b   = blockIdx.y;      // batch
  const int t0  = blockIdx.x << 4; // first frame index of this block

  // ---- twiddle tables (once per block) ----
  const float TWOPI = 6.283185307179586f;
  for (int i = tid; i < 512; i += 256) {
    float a = TWOPI * (float)i * (1.0f/512.0f);
    tw512[phys(i)] = { cosf(a), -sinf(a) };      // e^{-2pi i/512}
  }
  for (int i = tid; i < 513; i += 256) {
    float a = TWOPI * (float)i * (1.0f/1024.0f);
    wu[i] = { cosf(a), -sinf(a) };               // e^{-2pi i/1024}
  }
  __syncthreads();

  // ---- window preload (basis row 0 == hann window, since real(fb[0]) == 1) ----
  float2 wl[8];
  #pragma unroll
  for (int j = 0; j < 8; ++j) wl[j] = *(const float2*)&basis[2*(t + 64*j)];

  const float* xb = input + (size_t)b * L_IN;

  for (int fi = 0; fi < 4; ++fi) {
    const int tl = w*4 + fi;
    const int tt = t0 + tl;
    if (tt > 2048) continue;                     // wave-uniform
    const int s0 = tt*512 - 512;

    // ---- load + window + stage 0 (Ls=1, no twiddles) fused in registers ----
    // z[n] = xw[2n] + i*xw[2n+1], lane holds n = t + 64j  (== stage-0 read pattern)
    C2 x[8];
    if (tt != 0 && tt != 2048) {
      #pragma unroll
      for (int j = 0; j < 8; ++j) {
        float2 v = *(const float2*)&xb[s0 + 2*(t + 64*j)];
        x[j] = { v.x * wl[j].x, v.y * wl[j].y };
      }
    } else {                                     // reflect-pad edge frames
      #pragma unroll
      for (int j = 0; j < 8; ++j) {
        int e0 = s0 + 2*(t + 64*j), e1 = e0 + 1;
        int r0 = e0 < 0 ? -e0 : (e0 >= L_IN ? 2*L_IN - 2 - e0 : e0);
        int r1 = e1 < 0 ? -e1 : (e1 >= L_IN ? 2*L_IN - 2 - e1 : e1);
        x[j] = { xb[r0] * wl[j].x, xb[r1] * wl[j].y };
      }
    }
    C2 y[8];
    dft8(x, y);
    #pragma unroll
    for (int k = 0; k < 8; ++k) cf[w][phys(8*t + k)] = y[k];
    FENCE;

    // ---- stage 1 (Ls=8): tw = W_64^{m j} = W_512^{8 m j} ----
    {
      const int m = t & 7, g = t >> 3;
      C2 xs[8];
      #pragma unroll
      for (int j = 0; j < 8; ++j) xs[j] = cf[w][phys(t + 64*j)];
      #pragma unroll
      for (int j = 1; j < 8; ++j) xs[j] = cmul(xs[j], tw512[phys(m*j*8)]);
      dft8(xs, y);
      #pragma unroll
      for (int k = 0; k < 8; ++k) cf[w][phys(g*64 + m + 8*k)] = y[k];
    }
    FENCE;

    // ---- stage 2 (Ls=64): tw = W_512^{t j}; keep Z in regs, mirror to LDS ----
    C2 z[8];
    {
      C2 xs[8];
      #pragma unroll
      for (int j = 0; j < 8; ++j) xs[j] = cf[w][phys(t + 64*j)];
      #pragma unroll
      for (int j = 1; j < 8; ++j) xs[j] = cmul(xs[j], tw512[phys(t*j)]);
      dft8(xs, z);                               // z[k] = Z[t + 64k], natural order
      #pragma unroll
      for (int k = 0; k < 8; ++k) cf[w][phys(t + 64*k)] = z[k];
    }
    FENCE;

    // ---- real-FFT unpack + magnitude: bins k = t + 64j ----
    // X_k = A - i*W^k*B,  A = (Z_k + conj Z_{512-k})/2,  B = (Z_k - conj Z_{512-k})/2
    #pragma unroll
    for (int j = 0; j < 8; ++j) {
      const int k = t + 64*j;
      C2 Zk = z[j];                              // own value from registers
      C2 Zp = cf[w][phys((512 - k) & 511)];      // partner from LDS
      C2 W  = wu[k];
      float Are = 0.5f*(Zk.r + Zp.r), Aim = 0.5f*(Zk.i - Zp.i);
      float Bre = 0.5f*(Zk.r - Zp.r), Bim = 0.5f*(Zk.i + Zp.i);
      float Xr = Are + (W.r*Bim + W.i*Bre);
      float Xi = Aim - (W.r*Bre - W.i*Bim);
      mag[k][tl] = sqrtf(Xr*Xr + Xi*Xi);
    }
    if (t == 0) mag[512][tl] = fabsf(z[0].r - z[0].i);   // X[512] = ReZ0 - ImZ0
    FENCE;                                       // partner reads done before next frame overwrites cf
  }
  __syncthreads();

  // ---- coalesced output: 64 B chunks along t ----
  const size_t ob = (size_t)b * NBINS * T_FR;
  for (int idx = tid; idx < NBINS*16; idx += 256) {
    const int row = idx >> 4, tl = idx & 15, tt = t0 + tl;
    if (tt <= 2048) out[ob + (size_t)row * T_FR + tt] = mag[row][tl];
  }
}

extern "C" void kernel_launch(void* const* d_in, const int* in_sizes, int n_in,
                              void* d_out, int out_size, void* d_ws, size_t ws_size,
                              hipStream_t stream) {
  const float* input = (const float*)d_in[0];
  const float* basis = (const float*)d_in[1];
  float* out = (float*)d_out;
  // 129 frame-tiles of 16 (last tile: frame 2048 only) x 16 batches
  stft_fft<<<dim3(129, 16), 256, 0, stream>>>(input, basis, out);
}

// Round 9
// 54.261 us; speedup vs baseline: 2.1819x; 1.2737x over previous
//
#include <hip/hip_runtime.h>
#include <math.h>

#define L_IN   1048576
#define NBATCH 16
#define T_FR   2049
#define NBINS  513

// ---------------- complex helpers ----------------
struct C2 { float r, i; };
__device__ __forceinline__ C2 cadd(C2 a, C2 b){ return {a.r+b.r, a.i+b.i}; }
__device__ __forceinline__ C2 csub(C2 a, C2 b){ return {a.r-b.r, a.i-b.i}; }
__device__ __forceinline__ C2 cmul(C2 a, C2 b){ return {a.r*b.r - a.i*b.i, a.r*b.i + a.i*b.r}; }
__device__ __forceinline__ C2 cnegi(C2 a){ return {a.i, -a.r}; }            // a * (-i)
#define RSQ2 0.70710678118654752f
__device__ __forceinline__ C2 cw8 (C2 a){ return { RSQ2*(a.r+a.i),  RSQ2*(a.i-a.r)}; }  // a * w8
__device__ __forceinline__ C2 cw83(C2 a){ return { RSQ2*(a.i-a.r), -RSQ2*(a.r+a.i)}; }  // a * w8^3

// 8-point DFT, natural order in/out, w8 = e^{-i pi/4}. (verified: impulse at x1 -> y_k = w8^k)
__device__ __forceinline__ void dft8(const C2 x[8], C2 y[8]) {
  C2 ea0 = cadd(x[0], x[4]), ea1 = csub(x[0], x[4]);
  C2 eb0 = cadd(x[2], x[6]), eb1 = csub(x[2], x[6]);
  C2 oa0 = cadd(x[1], x[5]), oa1 = csub(x[1], x[5]);
  C2 ob0 = cadd(x[3], x[7]), ob1 = csub(x[3], x[7]);
  C2 E0 = cadd(ea0, eb0), E2 = csub(ea0, eb0);
  C2 nb = cnegi(eb1);
  C2 E1 = cadd(ea1, nb),  E3 = csub(ea1, nb);
  C2 O0 = cadd(oa0, ob0), O2 = csub(oa0, ob0);
  C2 no = cnegi(ob1);
  C2 O1 = cadd(oa1, no),  O3 = csub(oa1, no);
  y[0] = cadd(E0, O0);  y[4] = csub(E0, O0);
  C2 t1 = cw8(O1);      y[1] = cadd(E1, t1); y[5] = csub(E1, t1);
  C2 t2 = cnegi(O2);    y[2] = cadd(E2, t2); y[6] = csub(E2, t2);
  C2 t3 = cw83(O3);     y[3] = cadd(E3, t3); y[7] = csub(E3, t3);
}

// LDS bank-spread swizzle (bijective on [0,512)) — verified per access pattern in R8.
__device__ __forceinline__ int phys(int idx) { return idx ^ ((idx >> 4) & 15); }

#define FENCE do { asm volatile("s_waitcnt lgkmcnt(0)" ::: "memory"); \
                   __builtin_amdgcn_sched_barrier(0); } while (0)

#define TWOPI 6.283185307179586f

// raw (unwindowed) frame load; reflect only for edge frames (wave-uniform branch)
__device__ __forceinline__ void load_raw(float2 v[8], const float* __restrict__ xb,
                                         int tt, int t) {
  const int s0 = tt*512 - 512;
  if (tt != 0 && tt != 2048) {
    #pragma unroll
    for (int j = 0; j < 8; ++j) v[j] = *(const float2*)&xb[s0 + 2*(t + 64*j)];
  } else {
    #pragma unroll
    for (int j = 0; j < 8; ++j) {
      int e0 = s0 + 2*(t + 64*j), e1 = e0 + 1;
      int r0 = e0 < 0 ? -e0 : (e0 >= L_IN ? 2*L_IN - 2 - e0 : e0);
      int r1 = e1 < 0 ? -e1 : (e1 >= L_IN ? 2*L_IN - 2 - e1 : e1);
      v[j] = { xb[r0], xb[r1] };
    }
  }
}

// full per-frame pipeline: window -> 3x radix-8 Stockham -> real unpack -> mag stage
__device__ __forceinline__ void process_frame(const float2 v[8], const float2 wl[8],
    const C2 tws1[8], const C2 tws2[8], const C2 twu[8],
    C2* __restrict__ cfw, float (* __restrict__ mag)[17], int t, int tl)
{
  C2 x[8], y[8];
  #pragma unroll
  for (int j = 0; j < 8; ++j) x[j] = { v[j].x * wl[j].x, v[j].y * wl[j].y };
  dft8(x, y);                                   // stage 0 (Ls=1)
  #pragma unroll
  for (int k = 0; k < 8; ++k) cfw[phys(8*t + k)] = y[k];
  FENCE;
  {                                             // stage 1 (Ls=8): tw = W_64^{m j}
    const int m = t & 7, g = t >> 3;
    C2 xs[8];
    #pragma unroll
    for (int j = 0; j < 8; ++j) xs[j] = cfw[phys(t + 64*j)];
    #pragma unroll
    for (int j = 1; j < 8; ++j) xs[j] = cmul(xs[j], tws1[j]);
    dft8(xs, y);
    #pragma unroll
    for (int k = 0; k < 8; ++k) cfw[phys(g*64 + m + 8*k)] = y[k];
  }
  FENCE;
  C2 z[8];
  {                                             // stage 2 (Ls=64): tw = W_512^{t j}
    C2 xs[8];
    #pragma unroll
    for (int j = 0; j < 8; ++j) xs[j] = cfw[phys(t + 64*j)];
    #pragma unroll
    for (int j = 1; j < 8; ++j) xs[j] = cmul(xs[j], tws2[j]);
    dft8(xs, z);                                // z[k] = Z[t + 64k], natural order
    #pragma unroll
    for (int k = 0; k < 8; ++k) cfw[phys(t + 64*k)] = z[k];
  }
  FENCE;
  // real-FFT unpack + magnitude: X_k = A - i*W^k*B
  #pragma unroll
  for (int j = 0; j < 8; ++j) {
    const int k = t + 64*j;
    C2 Zk = z[j];                               // own value from registers
    C2 Zp = cfw[phys((512 - k) & 511)];         // partner from LDS
    C2 W  = twu[j];
    float Are = 0.5f*(Zk.r + Zp.r), Aim = 0.5f*(Zk.i - Zp.i);
    float Bre = 0.5f*(Zk.r - Zp.r), Bim = 0.5f*(Zk.i + Zp.i);
    float Xr = Are + (W.r*Bim + W.i*Bre);
    float Xi = Aim - (W.r*Bre - W.i*Bim);
    mag[k][tl] = sqrtf(Xr*Xr + Xi*Xi);
  }
  if (t == 0) mag[512][tl] = fabsf(z[0].r - z[0].i);   // X[512] = ReZ0 - ImZ0
  FENCE;                                        // partner reads done before next frame's writes
}

// One block = 16 consecutive frames of one batch; 4 waves x 4 frames, fully
// wave-local FFTs (no block barriers inside), twiddles in registers,
// next-frame global prefetch hides HBM/L3 latency under current frame's FFT.
__global__ __launch_bounds__(256, 3)
void stft_fft(const float* __restrict__ input,
              const float* __restrict__ basis,
              float* __restrict__ out)
{
  __shared__ C2    cf[4][512];     // per-wave exchange array (16 KB)
  __shared__ float mag[513][17];   // output transpose staging (34.9 KB) -> 51.3 KB total

  const int tid = threadIdx.x;
  const int t   = tid & 63;        // lane
  const int w   = tid >> 6;        // wave 0..3
  const int b   = blockIdx.y;      // batch
  const int t0  = blockIdx.x << 4; // first frame of this block

  // ---- per-lane twiddle registers (frame-invariant) ----
  C2 tws1[8], tws2[8], twu[8];
  {
    const int m = t & 7;
    #pragma unroll
    for (int j = 1; j < 8; ++j) {
      float s, c, a1 = (TWOPI/64.0f)  * (float)(m*j);
      __sincosf(a1, &s, &c); tws1[j] = { c, -s };
      float a2 = (TWOPI/512.0f) * (float)(t*j);
      __sincosf(a2, &s, &c); tws2[j] = { c, -s };
    }
    #pragma unroll
    for (int j = 0; j < 8; ++j) {
      float s, c, a = (TWOPI/1024.0f) * (float)(t + 64*j);
      __sincosf(a, &s, &c); twu[j] = { c, -s };
    }
  }

  // ---- window preload (basis row 0 == hann window, real(fb[0]) == 1) ----
  float2 wl[8];
  #pragma unroll
  for (int j = 0; j < 8; ++j) wl[j] = *(const float2*)&basis[2*(t + 64*j)];

  const float* xb = input + (size_t)b * L_IN;
  C2* cfw = cf[w];
  const int base = t0 + w*4;

  // ---- 4 frames per wave, ping-pong prefetch ----
  float2 v0[8], v1[8];
  if (base     <= 2048) load_raw(v0, xb, base,     t);
  if (base + 1 <= 2048) load_raw(v1, xb, base + 1, t);
  if (base     <= 2048) process_frame(v0, wl, tws1, tws2, twu, cfw, mag, t, w*4);
  if (base + 2 <= 2048) load_raw(v0, xb, base + 2, t);
  if (base + 1 <= 2048) process_frame(v1, wl, tws1, tws2, twu, cfw, mag, t, w*4 + 1);
  if (base + 3 <= 2048) load_raw(v1, xb, base + 3, t);
  if (base + 2 <= 2048) process_frame(v0, wl, tws1, tws2, twu, cfw, mag, t, w*4 + 2);
  if (base + 3 <= 2048) process_frame(v1, wl, tws1, tws2, twu, cfw, mag, t, w*4 + 3);

  __syncthreads();

  // ---- coalesced output: 64 B chunks along t ----
  const size_t ob = (size_t)b * NBINS * T_FR;
  for (int idx = tid; idx < NBINS*16; idx += 256) {
    const int row = idx >> 4, tl = idx & 15, tt = t0 + tl;
    if (tt <= 2048) out[ob + (size_t)row * T_FR + tt] = mag[row][tl];
  }
}

extern "C" void kernel_launch(void* const* d_in, const int* in_sizes, int n_in,
                              void* d_out, int out_size, void* d_ws, size_t ws_size,
                              hipStream_t stream) {
  const float* input = (const float*)d_in[0];
  const float* basis = (const float*)d_in[1];
  float* out = (float*)d_out;
  // 129 frame-tiles of 16 (last tile: frame 2048 only) x 16 batches
  stft_fft<<<dim3(129, 16), 256, 0, stream>>>(input, basis, out);
}